// Round 10
// baseline (3321.690 us; speedup 1.0000x reference)
//
#include <hip/hip_runtime.h>
#include <hip/hip_bf16.h>

// Problem constants (from reference)
#define Bb  32
#define Tt  12
#define Nn  5000
#define INc 2
#define Hh  128
#define HORc 12
#define Ee  80000
#define NTt (Bb*Nn)   // 160000

typedef float f4  __attribute__((ext_vector_type(4)));
typedef _Float16 h8 __attribute__((ext_vector_type(8)));
typedef _Float16 h4 __attribute__((ext_vector_type(4)));
typedef _Float16 h2 __attribute__((ext_vector_type(2)));

// hcL[.][172] (K=160 B-operand + K-ext); hL[.][140] persistent h (light kernel).
// HSTRIDE 172 / HLSTRIDE 140: round-7/9-proven strides (188K conflicts, negligible).
#define HSTRIDE 172
#define HLSTRIDE 140
#define GROUP_LDS (64*HSTRIDE)                   // mainm_g block (64-node group)
#define NGRAPH 79               // groups 0..78 contain nodes < Nn (graph part)
// k_light per-wave LDS: 16-node group
#define WAVE_HCL (16*HSTRIDE)
#define WAVE_HL  (16*HLSTRIDE)
#define WAVE_LLDS (WAVE_HCL + WAVE_HL)           // 4992 halfs = 9984 B

__device__ __forceinline__ float ldf(const void* p, size_t i, int isbf){
  return isbf ? __bfloat162float(((const __hip_bfloat16*)p)[i]) : ((const float*)p)[i];
}
__device__ __forceinline__ int eidx(const int* e, int i, int is64){
  return is64 ? e[2*i] : e[i];
}
// sigmoid/tanh via hardware exp+rcp.
__device__ __forceinline__ float sigm1(float x){
  return __builtin_amdgcn_rcpf(1.f + __expf(-x));
}
__device__ __forceinline__ float tanh1(float x){
  return 1.f - 2.f*__builtin_amdgcn_rcpf(1.f + __expf(2.f*x));
}

// ---------------- dtype detection ----------------
__global__ __launch_bounds__(256) void k_detect(const void* W2raw, const int* edge32, int* flags){
  __shared__ int cnt_bf, cnt_odd;
  if (threadIdx.x==0){ cnt_bf=0; cnt_odd=0; }
  __syncthreads();
  {
    unsigned w = ((const unsigned*)W2raw)[threadIdx.x];
    unsigned hb = (w>>8)&0x7Fu;
    if (hb>=0x34u && hb<=0x3Fu) atomicAdd(&cnt_bf,1);
  }
  if (threadIdx.x < 128){
    if (edge32[2*threadIdx.x+1] != 0) atomicAdd(&cnt_odd,1);
  }
  __syncthreads();
  if (threadIdx.x==0){
    flags[0] = (cnt_bf >= 128) ? 1 : 0;
    flags[1] = (cnt_odd == 0) ? 1 : 0;
  }
}

// ---------------- graph precompute ----------------
__global__ __launch_bounds__(256) void k_deg_cnt(const int* __restrict__ edge, int* deg, int* cnt,
                                                 const int* __restrict__ flags){
  int id = blockIdx.x*256 + threadIdx.x;
  int is64 = flags[1];
  if (id < Ee){
    atomicAdd(&deg[eidx(edge, id, is64)], 1);
    atomicAdd(&cnt[eidx(edge, Ee+id, is64)], 1);
  }
}

__global__ __launch_bounds__(256) void k_dis(const int* __restrict__ deg, float* dis){
  int id = blockIdx.x*256 + threadIdx.x;
  if (id < Nn){
    int d = deg[id];
    dis[id] = d > 0 ? rsqrtf((float)d) : 0.f;
  }
}

__global__ __launch_bounds__(1024) void k_scan(const int* __restrict__ cnt, int* rowptr){
  __shared__ int part[1024];
  int t = threadIdx.x;
  int base = t*5;
  int s = 0;
  #pragma unroll
  for (int j=0;j<5;j++){ int idx=base+j; if (idx<Nn) s += cnt[idx]; }
  part[t] = s; __syncthreads();
  for (int off=1; off<1024; off<<=1){
    int add = (t>=off) ? part[t-off] : 0;
    __syncthreads();
    part[t] += add;
    __syncthreads();
  }
  int run = (t>0) ? part[t-1] : 0;
  #pragma unroll
  for (int j=0;j<5;j++){
    int idx = base+j;
    if (idx < Nn){ rowptr[idx] = run; run += cnt[idx]; }
  }
  if (t == 1023) rowptr[Nn] = part[1023];
}

__global__ __launch_bounds__(256) void k_fill(const int* __restrict__ edge,
                                              const int* __restrict__ rowptr,
                                              int* fillc, int* csr,
                                              const int* __restrict__ flags){
  int id = blockIdx.x*256 + threadIdx.x;
  int is64 = flags[1];
  if (id < Ee){
    int d = eidx(edge, Ee+id, is64);
    int pos = atomicAdd(&fillc[d], 1);
    csr[rowptr[d] + pos] = eidx(edge, id, is64);
  }
}

// ---------------- weight precompute (element-parallel) ----------------
__global__ __launch_bounds__(128) void k_wx(
  const void* __restrict__ W1, const void* __restrict__ b1,
  const void* __restrict__ W2, const void* __restrict__ b2,
  const void* __restrict__ Wz, const void* __restrict__ bz,
  const void* __restrict__ Wr, const void* __restrict__ br,
  const void* __restrict__ Wc, const void* __restrict__ bc,
  _Float16* __restrict__ Wext, _Float16* __restrict__ Whc,
  const int* __restrict__ flags)
{
  int bid = blockIdx.x, f = threadIdx.x;
  int isbf = flags[0];
  if (bid < 640){
    int s = bid/160, k = bid - s*160;
    float v = 0.f;
    if (k < 128){
      if (s == 0)
        v = ldf(W2,(size_t)k*128+f,isbf) - ldf(W2,(size_t)(2*128+k)*128+f,isbf);
      else {
        const void* Wg = (s==1)?Wz:((s==2)?Wr:Wc);
        v = ldf(Wg,(size_t)(128+k)*128+f,isbf);
      }
    } else if (s == 0){
      v = (k==128) ? ldf(b2,f,isbf) : 0.f;
    } else if (k < 134){
      const void* Wg = (s==1)?Wz:((s==2)?Wr:Wc);
      int q = k - 128;
      float acc = 0.f;
      for (int j=0;j<128;j++) acc += ldf(W1,(size_t)q*128+j,isbf)*ldf(Wg,(size_t)j*128+f,isbf);
      v = acc;
    } else if (k == 134){
      const void* Wg = (s==1)?Wz:((s==2)?Wr:Wc);
      const void* bg = (s==1)?bz:((s==2)?br:bc);
      float acc = ldf(bg,f,isbf);
      for (int j=0;j<128;j++) acc += ldf(b1,j,isbf)*ldf(Wg,(size_t)j*128+f,isbf);
      v = acc;
    }
    Wext[(size_t)(s*128+f)*160 + k] = (_Float16)v;
  } else {
    int k = bid - 640;  // 0..255
    float v = (k < 128) ? ldf(W2,(size_t)(128+k)*128+f,isbf)
                        : 2.f*ldf(W2,(size_t)(2*128+(k-128))*128+f,isbf);
    Whc[(size_t)f*256 + k] = (_Float16)v;
  }
}

// ---------------- x propagation (all timesteps at once) ----------------
__global__ __launch_bounds__(256) void k_px1(
  const void* __restrict__ x, const float* __restrict__ dis,
  const int* __restrict__ rowptr, const int* __restrict__ csr, float* __restrict__ px1,
  const int* __restrict__ flags)
{
  int id = blockIdx.x*256 + threadIdx.x;
  int isbf = flags[0];
  if (id < Tt*Nn){
    int t = id / Nn, n = id - t*Nn;
    int e0 = rowptr[n], e1 = rowptr[n+1];
    float a0=0.f, a1=0.f;
    for (int e=e0;e<e1;e++){
      int s = csr[e]; float ds = dis[s];
      size_t xb = (size_t)(t*Nn+s)*2;
      a0 += ds*ldf(x,xb+0,isbf); a1 += ds*ldf(x,xb+1,isbf);
    }
    float dn = -dis[n];
    px1[id*2+0] = dn*a0; px1[id*2+1] = dn*a1;
  }
}

__global__ __launch_bounds__(256) void k_px2(
  const float* __restrict__ px1, const float* __restrict__ dis,
  const int* __restrict__ rowptr, const int* __restrict__ csr, float* __restrict__ px2)
{
  int id = blockIdx.x*256 + threadIdx.x;
  if (id < Tt*Nn){
    int t = id / Nn, n = id - t*Nn;
    int e0 = rowptr[n], e1 = rowptr[n+1];
    float a0=0.f, a1=0.f;
    for (int e=e0;e<e1;e++){
      int s = csr[e]; float ds = dis[s];
      const float* pp = px1 + (size_t)(t*Nn+s)*2;
      a0 += ds*pp[0]; a1 += ds*pp[1];
    }
    float dn = -dis[n];
    px2[id*2+0] = dn*a0; px2[id*2+1] = dn*a1;
  }
}

// ---------------- per-step h propagation (fp16, 4 nodes/block) ----------------
__global__ __launch_bounds__(256) void k_ph1(
  const _Float16* __restrict__ h16, const float* __restrict__ dis,
  const int* __restrict__ rowptr, const int* __restrict__ csr,
  _Float16* __restrict__ phh)
{
  int n = blockIdx.x*4 + (threadIdx.x>>6);
  int f2 = threadIdx.x & 63;
  int e0 = rowptr[n], e1 = rowptr[n+1];
  float a0=0.f, a1=0.f, b0=0.f, b1=0.f;
  int e = e0;
  for (; e+3 < e1; e += 4){
    int s0=csr[e], s1=csr[e+1], s2=csr[e+2], s3=csr[e+3];
    float d0=dis[s0], d1=dis[s1], d2=dis[s2], d3=dis[s3];
    h2 v0 = *(const h2*)(h16 + (size_t)s0*128 + 2*f2);
    h2 v1 = *(const h2*)(h16 + (size_t)s1*128 + 2*f2);
    h2 v2 = *(const h2*)(h16 + (size_t)s2*128 + 2*f2);
    h2 v3 = *(const h2*)(h16 + (size_t)s3*128 + 2*f2);
    a0 += d0*(float)v0[0]; a1 += d0*(float)v0[1];
    b0 += d1*(float)v1[0]; b1 += d1*(float)v1[1];
    a0 += d2*(float)v2[0]; a1 += d2*(float)v2[1];
    b0 += d3*(float)v3[0]; b1 += d3*(float)v3[1];
  }
  for (; e < e1; e++){
    int s = csr[e]; float ds = dis[s];
    h2 v = *(const h2*)(h16 + (size_t)s*128 + 2*f2);
    a0 += ds*(float)v[0]; a1 += ds*(float)v[1];
  }
  a0 += b0; a1 += b1;
  float dn = -dis[n];
  h2 o; o[0]=(_Float16)(dn*a0); o[1]=(_Float16)(dn*a1);
  *(h2*)(phh + (size_t)n*256 + 2*f2) = o;
}

__global__ __launch_bounds__(256) void k_ph2(
  const float* __restrict__ dis,
  const int* __restrict__ rowptr, const int* __restrict__ csr,
  _Float16* __restrict__ phh)
{
  int n = blockIdx.x*4 + (threadIdx.x>>6);
  int f2 = threadIdx.x & 63;
  int e0 = rowptr[n], e1 = rowptr[n+1];
  float a0=0.f, a1=0.f, b0=0.f, b1=0.f;
  int e = e0;
  for (; e+3 < e1; e += 4){
    int s0=csr[e], s1=csr[e+1], s2=csr[e+2], s3=csr[e+3];
    float d0=dis[s0], d1=dis[s1], d2=dis[s2], d3=dis[s3];
    h2 v0 = *(const h2*)(phh + (size_t)s0*256 + 2*f2);
    h2 v1 = *(const h2*)(phh + (size_t)s1*256 + 2*f2);
    h2 v2 = *(const h2*)(phh + (size_t)s2*256 + 2*f2);
    h2 v3 = *(const h2*)(phh + (size_t)s3*256 + 2*f2);
    a0 += d0*(float)v0[0]; a1 += d0*(float)v0[1];
    b0 += d1*(float)v1[0]; b1 += d1*(float)v1[1];
    a0 += d2*(float)v2[0]; a1 += d2*(float)v2[1];
    b0 += d3*(float)v3[0]; b1 += d3*(float)v3[1];
  }
  for (; e < e1; e++){
    int s = csr[e]; float ds = dis[s];
    h2 v = *(const h2*)(phh + (size_t)s*256 + 2*f2);
    a0 += ds*(float)v[0]; a1 += ds*(float)v[1];
  }
  a0 += b0; a1 += b1;
  float dn = -dis[n];
  h2 o; o[0]=(_Float16)(dn*a0); o[1]=(_Float16)(dn*a1);
  *(h2*)(phh + (size_t)n*256 + 128 + 2*f2) = o;
}

// ---------------- graph groups: per-step GRU (round-4 body, 79 WGs) ----------------
__global__ __launch_bounds__(256, 2) void k_mainm_g(
    _Float16* __restrict__ h16, const void* __restrict__ x,
    const float* __restrict__ px1, const float* __restrict__ px2,
    const _Float16* __restrict__ phh,
    const _Float16* __restrict__ Wext, const _Float16* __restrict__ Whc,
    const int* __restrict__ flags, int t)
{
  __shared__ _Float16 hcL[GROUP_LDS];   // 22016 B
  int tid = threadIdx.x;
  int w = tid >> 6, lane = tid & 63;
  int fp = w;
  int gbase = blockIdx.x*64;
  int n16 = lane & 15, g = lane >> 4, q8 = g*8;

  if (tid < 64){
    int n = tid;
    _Float16* row = hcL + n*HSTRIDE;
    for (int k=135;k<160;k++) row[k] = (_Float16)0.f;
    int isbf = flags[0];
    int i = gbase + n;
    int b = i / Nn, nn2 = i - b*Nn;
    size_t xb = ((size_t)(b*Tt + t)*Nn + nn2)*2;
    float x0 = ldf(x,xb+0,isbf), x1 = ldf(x,xb+1,isbf);
    float u1a=0.f,u1b=0.f,u2a=-x0,u2b=-x1;   // nodes >= Nn: Tx1=0, Tx2=-x
    if (i < Nn){
      u1a = px1[(t*Nn+i)*2+0]; u1b = px1[(t*Nn+i)*2+1];
      u2a = 2.f*px2[(t*Nn+i)*2+0] - x0; u2b = 2.f*px2[(t*Nn+i)*2+1] - x1;
    }
    row[128]=(_Float16)x0;  row[129]=(_Float16)x1;
    row[130]=(_Float16)u1a; row[131]=(_Float16)u1b;
    row[132]=(_Float16)u2a; row[133]=(_Float16)u2b;
    row[134]=(_Float16)1.f;
  }

  h8 zz = {0,0,0,0,0,0,0,0};
  h8 biasv = zz;
  if (g==0) biasv[0] = (_Float16)1.f;
  f4 z4 = {0.f,0.f,0.f,0.f};

  // stage 0
  f4 acc[4][2];
  #pragma unroll
  for (int tl=0;tl<4;tl++){ acc[tl][0]=z4; acc[tl][1]=z4; }
  {
    h8 bf[4][4];
    #pragma unroll
    for (int tl=0;tl<4;tl++){
      const _Float16* hp = h16 + (size_t)(gbase + tl*16 + n16)*128 + q8;
      #pragma unroll
      for (int ks=0;ks<4;ks++) bf[tl][ks] = *(const h8*)(hp + ks*32);
    }
    const _Float16* Wa = Wext + (size_t)(fp*32 + n16)*160 + q8;
    #pragma unroll
    for (int ks=0; ks<5; ks++){
      h8 a0 = *(const h8*)(Wa + ks*32);
      h8 a1 = *(const h8*)(Wa + 16*160 + ks*32);
      #pragma unroll
      for (int tl=0;tl<4;tl++){
        h8 b = (ks<4) ? bf[tl][ks] : biasv;
        acc[tl][0] = __builtin_amdgcn_mfma_f32_16x16x32_f16(a0, b, acc[tl][0], 0,0,0);
        acc[tl][1] = __builtin_amdgcn_mfma_f32_16x16x32_f16(a1, b, acc[tl][1], 0,0,0);
      }
    }
  }
  {
    const _Float16* Wb = Whc + (size_t)(fp*32 + n16)*256 + q8;
    #pragma unroll
    for (int pass=0; pass<2; pass++){
      h8 bg[2][8];
      #pragma unroll
      for (int tt=0;tt<2;tt++){
        int node = gbase + (pass*2+tt)*16 + n16;
        bool ok = node < Nn;
        const _Float16* pp = phh + (size_t)(ok ? node : 0)*256 + q8;
        #pragma unroll
        for (int ks=0;ks<8;ks++){
          h8 v = *(const h8*)(pp + ks*32);
          bg[tt][ks] = ok ? v : zz;
        }
      }
      #pragma unroll
      for (int ks=0; ks<8; ks++){
        h8 a0 = *(const h8*)(Wb + ks*32);
        h8 a1 = *(const h8*)(Wb + 16*256 + ks*32);
        #pragma unroll
        for (int tt=0;tt<2;tt++){
          acc[pass*2+tt][0] = __builtin_amdgcn_mfma_f32_16x16x32_f16(a0, bg[tt][ks], acc[pass*2+tt][0], 0,0,0);
          acc[pass*2+tt][1] = __builtin_amdgcn_mfma_f32_16x16x32_f16(a1, bg[tt][ks], acc[pass*2+tt][1], 0,0,0);
        }
      }
    }
  }
  #pragma unroll
  for (int tl=0;tl<4;tl++)
    #pragma unroll
    for (int hh=0;hh<2;hh++){
      int fb = fp*32 + hh*16 + g*4;
      f4 a = acc[tl][hh];
      h4 o;
      #pragma unroll
      for (int r=0;r<4;r++) o[r] = (_Float16)a[r];
      *(h4*)&hcL[(tl*16+n16)*HSTRIDE + fb] = o;
    }

  __syncthreads();

  h8 ba[4][5];
  #pragma unroll
  for (int tl=0;tl<4;tl++)
    #pragma unroll
    for (int ks=0;ks<5;ks++)
      ba[tl][ks] = *(const h8*)&hcL[(tl*16+n16)*HSTRIDE + ks*32 + q8];

  // stage 1: z
  f4 accZ[4][2];
  #pragma unroll
  for (int tl=0;tl<4;tl++){ accZ[tl][0]=z4; accZ[tl][1]=z4; }
  {
    const _Float16* Wa = Wext + 1*20480 + (size_t)(fp*32 + n16)*160 + q8;
    #pragma unroll
    for (int ks=0; ks<5; ks++){
      h8 a0 = *(const h8*)(Wa + ks*32);
      h8 a1 = *(const h8*)(Wa + 16*160 + ks*32);
      #pragma unroll
      for (int tl=0;tl<4;tl++){
        accZ[tl][0] = __builtin_amdgcn_mfma_f32_16x16x32_f16(a0, ba[tl][ks], accZ[tl][0], 0,0,0);
        accZ[tl][1] = __builtin_amdgcn_mfma_f32_16x16x32_f16(a1, ba[tl][ks], accZ[tl][1], 0,0,0);
      }
    }
  }
  h4 zr[4][2];
  #pragma unroll
  for (int tl=0;tl<4;tl++)
    #pragma unroll
    for (int hh=0;hh<2;hh++){
      f4 a = accZ[tl][hh];
      h4 o;
      #pragma unroll
      for (int r=0;r<4;r++) o[r] = (_Float16)sigm1(a[r]);
      zr[tl][hh] = o;
    }

  // stage 2: r
  f4 accR[4][2];
  #pragma unroll
  for (int tl=0;tl<4;tl++){ accR[tl][0]=z4; accR[tl][1]=z4; }
  {
    const _Float16* Wa = Wext + 2*20480 + (size_t)(fp*32 + n16)*160 + q8;
    #pragma unroll
    for (int ks=0; ks<5; ks++){
      h8 a0 = *(const h8*)(Wa + ks*32);
      h8 a1 = *(const h8*)(Wa + 16*160 + ks*32);
      #pragma unroll
      for (int tl=0;tl<4;tl++){
        accR[tl][0] = __builtin_amdgcn_mfma_f32_16x16x32_f16(a0, ba[tl][ks], accR[tl][0], 0,0,0);
        accR[tl][1] = __builtin_amdgcn_mfma_f32_16x16x32_f16(a1, ba[tl][ks], accR[tl][1], 0,0,0);
      }
    }
  }
  #pragma unroll
  for (int tl=0;tl<4;tl++)
    #pragma unroll
    for (int hh=0;hh<2;hh++){
      int fb = fp*32 + hh*16 + g*4;
      int nn = tl*16 + n16;
      h4 hcv = *(const h4*)&hcL[nn*HSTRIDE + fb];
      f4 a = accR[tl][hh];
      h4 o;
      #pragma unroll
      for (int r=0;r<4;r++) o[r] = (_Float16)(sigm1(a[r]) * (float)hcv[r]);
      *(h4*)&hcL[nn*HSTRIDE + fb] = o;
    }

  __syncthreads();

  // stage 3: c + blend
  h8 bc[4][5];
  #pragma unroll
  for (int tl=0;tl<4;tl++)
    #pragma unroll
    for (int ks=0;ks<5;ks++)
      bc[tl][ks] = *(const h8*)&hcL[(tl*16+n16)*HSTRIDE + ks*32 + q8];

  f4 accC[4][2];
  #pragma unroll
  for (int tl=0;tl<4;tl++){ accC[tl][0]=z4; accC[tl][1]=z4; }
  {
    const _Float16* Wa = Wext + 3*20480 + (size_t)(fp*32 + n16)*160 + q8;
    #pragma unroll
    for (int ks=0; ks<5; ks++){
      h8 a0 = *(const h8*)(Wa + ks*32);
      h8 a1 = *(const h8*)(Wa + 16*160 + ks*32);
      #pragma unroll
      for (int tl=0;tl<4;tl++){
        accC[tl][0] = __builtin_amdgcn_mfma_f32_16x16x32_f16(a0, bc[tl][ks], accC[tl][0], 0,0,0);
        accC[tl][1] = __builtin_amdgcn_mfma_f32_16x16x32_f16(a1, bc[tl][ks], accC[tl][1], 0,0,0);
      }
    }
  }
  #pragma unroll
  for (int tl=0;tl<4;tl++)
    #pragma unroll
    for (int hh=0;hh<2;hh++){
      int fb = fp*32 + hh*16 + g*4;
      int nn = tl*16 + n16;
      int gi = gbase + nn;
      h4 ho = *(const h4*)(h16 + (size_t)gi*128 + fb);
      h4 zv = zr[tl][hh];
      f4 a = accC[tl][hh];
      h4 o;
      #pragma unroll
      for (int r=0;r<4;r++){
        float z = (float)zv[r];
        o[r] = (_Float16)(z*(float)ho[r] + (1.f - z)*tanh1(a[r]));
      }
      *(h4*)(h16 + (size_t)gi*128 + fb) = o;
    }
}

// ---------------- light groups: 12 timesteps fused, BARRIER-FREE per-wave ----------------
// Rounds 2-9 invariant: ~30 64-node group-steps/us in EVERY barrier-lockstep config
// (k_light runs at ~330 TF effective, 17% of f16 ceiling). The common structure was
// 3-4 __syncthreads per step forcing 4-wave lockstep at ~2 resident blocks/CU.
// v4: each WAVE owns 16 nodes x all 128 features -> hc/z/r/c produced and consumed
// by the same wave; LDS staging needs only same-wave lgkmcnt ordering (round-0-proven
// pattern) -> ZERO barriers. Registers: bf[4]=16, ba[5]=20, zr[4][2]=16 -> ~100 VGPR
// (under the 128 cliff; r7 lesson). LDS 4x9984=39936 B -> 4 blocks/CU, 16 waves/CU cap.
// x for step t+1 prefetched during step t (hides HBM latency).

__global__ __launch_bounds__(256) void k_light(
    _Float16* __restrict__ h16, const void* __restrict__ x,
    const _Float16* __restrict__ Wext, const int* __restrict__ flags)
{
  __shared__ _Float16 smem[4*WAVE_LLDS];   // 39936 B
  int tid = threadIdx.x;
  int w = tid >> 6, lane = tid & 63;
  _Float16* hcL = smem + w*WAVE_LLDS;
  _Float16* hL  = hcL + WAVE_HCL;
  int gbase = NGRAPH*64 + (blockIdx.x*4 + w)*16;   // 16-node group per wave
  int n16 = lane & 15, g = lane >> 4, q8 = g*8;
  int isbf = flags[0];

  // per-wave init: hL = 0 (h0 = 0), constant K-ext cols. No cross-wave sharing.
  for (int idx = lane; idx < WAVE_HL; idx += 64) hL[idx] = (_Float16)0.f;
  size_t xbase = 0;
  float x0 = 0.f, x1 = 0.f;
  if (lane < 16){
    _Float16* row = hcL + lane*HSTRIDE;
    for (int k=130;k<160;k++) row[k] = (_Float16)0.f;  // u1=0 fixed; 135..159 pad
    row[134] = (_Float16)1.f;                          // bias slot (stages 1-3)
    int i = gbase + lane;
    int b = i / Nn, nn2 = i - b*Nn;
    xbase = ((size_t)b*Tt*Nn + (size_t)nn2)*2;
    x0 = ldf(x,xbase+0,isbf); x1 = ldf(x,xbase+1,isbf);   // t=0 prefetch
  }

  h8 zz = {0,0,0,0,0,0,0,0};
  h8 biasv = zz;
  if (g==0) biasv[0] = (_Float16)1.f;   // k=128 bias col (stage 0)
  f4 z4 = {0.f,0.f,0.f,0.f};

  #pragma unroll 1
  for (int t = 0; t < Tt; ++t){
    // per-step K-ext: {x0, x1, 0, 0, -x0, -x1}; prefetch next step's x
    float x0n = 0.f, x1n = 0.f;
    if (lane < 16){
      _Float16* row = hcL + lane*HSTRIDE;
      row[128]=(_Float16)x0;     row[129]=(_Float16)x1;
      row[132]=(_Float16)(-x0);  row[133]=(_Float16)(-x1);
      if (t+1 < Tt){
        size_t xb = xbase + (size_t)(t+1)*(Nn*2);
        x0n = ldf(x,xb+0,isbf); x1n = ldf(x,xb+1,isbf);
      }
    }

    // ---- stage 0: hc = h@(W2[0]-W2[2]) + b2 (all 4 panels, own 16 nodes) ----
    {
      h8 bf[4];
      #pragma unroll
      for (int ks=0;ks<4;ks++) bf[ks] = *(const h8*)(hL + n16*HLSTRIDE + ks*32 + q8);
      #pragma unroll
      for (int fp=0; fp<4; fp++){
        f4 a0c=z4, a1c=z4;
        const _Float16* Wa = Wext + (size_t)(fp*32 + n16)*160 + q8;
        #pragma unroll
        for (int ks=0; ks<5; ks++){
          h8 a0 = *(const h8*)(Wa + ks*32);
          h8 a1 = *(const h8*)(Wa + 16*160 + ks*32);
          h8 b = (ks<4) ? bf[ks] : biasv;
          a0c = __builtin_amdgcn_mfma_f32_16x16x32_f16(a0, b, a0c, 0,0,0);
          a1c = __builtin_amdgcn_mfma_f32_16x16x32_f16(a1, b, a1c, 0,0,0);
        }
        h4 o0, o1;
        #pragma unroll
        for (int r=0;r<4;r++){ o0[r]=(_Float16)a0c[r]; o1[r]=(_Float16)a1c[r]; }
        *(h4*)&hcL[n16*HSTRIDE + fp*32 + g*4]      = o0;
        *(h4*)&hcL[n16*HSTRIDE + fp*32 + 16 + g*4] = o1;
      }
    }

    // B operand (full K=160) reg-cached for stages 1-2 (same-wave lgkmcnt ordering)
    h8 ba[5];
    #pragma unroll
    for (int ks=0;ks<5;ks++) ba[ks] = *(const h8*)&hcL[n16*HSTRIDE + ks*32 + q8];

    // ---- stage 1: z (registers only) ----
    h4 zr[4][2];
    #pragma unroll
    for (int fp=0; fp<4; fp++){
      f4 a0c=z4, a1c=z4;
      const _Float16* Wa = Wext + 1*20480 + (size_t)(fp*32 + n16)*160 + q8;
      #pragma unroll
      for (int ks=0; ks<5; ks++){
        h8 a0 = *(const h8*)(Wa + ks*32);
        h8 a1 = *(const h8*)(Wa + 16*160 + ks*32);
        a0c = __builtin_amdgcn_mfma_f32_16x16x32_f16(a0, ba[ks], a0c, 0,0,0);
        a1c = __builtin_amdgcn_mfma_f32_16x16x32_f16(a1, ba[ks], a1c, 0,0,0);
      }
      h4 o0, o1;
      #pragma unroll
      for (int r=0;r<4;r++){ o0[r]=(_Float16)sigm1(a0c[r]); o1[r]=(_Float16)sigm1(a1c[r]); }
      zr[fp][0]=o0; zr[fp][1]=o1;
    }

    // ---- stage 2: r, overwrite own hcL cols with r*hc ----
    #pragma unroll
    for (int fp=0; fp<4; fp++){
      f4 a0c=z4, a1c=z4;
      const _Float16* Wa = Wext + 2*20480 + (size_t)(fp*32 + n16)*160 + q8;
      #pragma unroll
      for (int ks=0; ks<5; ks++){
        h8 a0 = *(const h8*)(Wa + ks*32);
        h8 a1 = *(const h8*)(Wa + 16*160 + ks*32);
        a0c = __builtin_amdgcn_mfma_f32_16x16x32_f16(a0, ba[ks], a0c, 0,0,0);
        a1c = __builtin_amdgcn_mfma_f32_16x16x32_f16(a1, ba[ks], a1c, 0,0,0);
      }
      h4 hc0 = *(const h4*)&hcL[n16*HSTRIDE + fp*32 + g*4];
      h4 hc1 = *(const h4*)&hcL[n16*HSTRIDE + fp*32 + 16 + g*4];
      h4 o0, o1;
      #pragma unroll
      for (int r=0;r<4;r++){
        o0[r] = (_Float16)(sigm1(a0c[r]) * (float)hc0[r]);
        o1[r] = (_Float16)(sigm1(a1c[r]) * (float)hc1[r]);
      }
      *(h4*)&hcL[n16*HSTRIDE + fp*32 + g*4]      = o0;
      *(h4*)&hcL[n16*HSTRIDE + fp*32 + 16 + g*4] = o1;
    }

    // ---- stage 3: c + blend, write h_new to hL ----
    {
      h8 bc[5];
      #pragma unroll
      for (int ks=0;ks<5;ks++) bc[ks] = *(const h8*)&hcL[n16*HSTRIDE + ks*32 + q8];
      #pragma unroll
      for (int fp=0; fp<4; fp++){
        f4 a0c=z4, a1c=z4;
        const _Float16* Wa = Wext + 3*20480 + (size_t)(fp*32 + n16)*160 + q8;
        #pragma unroll
        for (int ks=0; ks<5; ks++){
          h8 a0 = *(const h8*)(Wa + ks*32);
          h8 a1 = *(const h8*)(Wa + 16*160 + ks*32);
          a0c = __builtin_amdgcn_mfma_f32_16x16x32_f16(a0, bc[ks], a0c, 0,0,0);
          a1c = __builtin_amdgcn_mfma_f32_16x16x32_f16(a1, bc[ks], a1c, 0,0,0);
        }
        h4 h0 = *(const h4*)&hL[n16*HLSTRIDE + fp*32 + g*4];
        h4 h1 = *(const h4*)&hL[n16*HLSTRIDE + fp*32 + 16 + g*4];
        h4 zv0 = zr[fp][0], zv1 = zr[fp][1];
        h4 o0, o1;
        #pragma unroll
        for (int r=0;r<4;r++){
          float z0 = (float)zv0[r], z1 = (float)zv1[r];
          o0[r] = (_Float16)(z0*(float)h0[r] + (1.f - z0)*tanh1(a0c[r]));
          o1[r] = (_Float16)(z1*(float)h1[r] + (1.f - z1)*tanh1(a1c[r]));
        }
        *(h4*)&hL[n16*HLSTRIDE + fp*32 + g*4]      = o0;
        *(h4*)&hL[n16*HLSTRIDE + fp*32 + 16 + g*4] = o1;
      }
    }

    x0 = x0n; x1 = x1n;
  }

  // write final h to global for k_out (own data, own LDS region; no barrier)
  for (int e = lane; e < 16*16; e += 64){
    int row = e >> 4, c = e & 15;
    *(h8*)(h16 + (size_t)(gbase + row)*128 + c*8) = *(const h8*)&hL[row*HLSTRIDE + c*8];
  }
}

// ---------------- output projection ----------------
__global__ __launch_bounds__(256) void k_out(
  const _Float16* __restrict__ h16, const void* __restrict__ Wo,
  const void* __restrict__ bo, void* __restrict__ out,
  const int* __restrict__ flags)
{
  __shared__ float wol[128*HORc];
  __shared__ float wob[HORc];
  int isbf = flags[0];
  for (int idx=threadIdx.x; idx<128*HORc; idx+=256) wol[idx] = ldf(Wo, idx, isbf);
  if (threadIdx.x < HORc) wob[threadIdx.x] = ldf(bo, threadIdx.x, isbf);
  __syncthreads();

  int i = blockIdx.x*256 + threadIdx.x;
  if (i < NTt){
    float acc[HORc];
    #pragma unroll
    for (int j=0;j<HORc;j++) acc[j] = wob[j];
    const _Float16* hp = h16 + (size_t)i*128;
    for (int kb=0;kb<16;kb++){
      h8 hv = *(const h8*)(hp + kb*8);
      #pragma unroll
      for (int j=0;j<8;j++){
        float hvf = (float)hv[j];
        #pragma unroll
        for (int jj=0;jj<HORc;jj++) acc[jj] += hvf * wol[(kb*8+j)*HORc + jj];
      }
    }
    int b = i / Nn, n = i - b*Nn;
    #pragma unroll
    for (int j=0;j<HORc;j++){
      size_t oi = (size_t)(b*HORc+j)*Nn + n;
      if (isbf) ((__hip_bfloat16*)out)[oi] = __float2bfloat16(acc[j]);
      else      ((float*)out)[oi] = acc[j];
    }
  }
}

// ---------------- host ----------------
extern "C" void kernel_launch(void* const* d_in, const int* in_sizes, int n_in,
                              void* d_out, int out_size, void* d_ws, size_t ws_size,
                              hipStream_t stream) {
  (void)in_sizes; (void)n_in; (void)out_size; (void)ws_size;
  const void* x   = d_in[0];
  const int*  edge= (const int*)d_in[1];
  const void* W1  = d_in[2];
  const void* b1  = d_in[3];
  const void* W2  = d_in[4];
  const void* b2  = d_in[5];
  const void* Wz  = d_in[6];
  const void* bz  = d_in[7];
  const void* Wr  = d_in[8];
  const void* br  = d_in[9];
  const void* Wc  = d_in[10];
  const void* bc  = d_in[11];
  const void* Wo  = d_in[12];
  const void* bo  = d_in[13];

  char* ws = (char*)d_ws;
  size_t off = 0;
  auto alloc = [&](size_t bytes)->char*{
    char* p = ws + off;
    off += (bytes + 255) & ~(size_t)255;
    return p;
  };
  _Float16* h16  = (_Float16*)alloc((size_t)NTt*128*2);   // 41 MB, zeroed
  int*   deg   = (int*)  alloc(Nn*4);                     // zeroed
  int*   cnt   = (int*)  alloc(Nn*4);                     // zeroed
  int*   fillc = (int*)  alloc(Nn*4);                     // zeroed
  size_t zlen = off;
  int*   flags = (int*)  alloc(16*4);
  float* dis   = (float*)alloc(Nn*4);
  int*   rowptr= (int*)  alloc((Nn+1)*4);
  int*   csr   = (int*)  alloc(Ee*4);
  float* px1   = (float*)alloc((size_t)Tt*Nn*2*4);
  float* px2   = (float*)alloc((size_t)Tt*Nn*2*4);
  _Float16* phh  = (_Float16*)alloc((size_t)5120*256*2);  // ph1|ph2 fp16 rows (padded)
  _Float16* Wext = (_Float16*)alloc((size_t)4*128*160*2);
  _Float16* Whc  = (_Float16*)alloc((size_t)128*256*2);

  hipMemsetAsync(d_ws, 0, zlen, stream);

  k_detect <<<1,256,0,stream>>>(W2, edge, flags);
  k_deg_cnt<<<(Ee+255)/256,256,0,stream>>>(edge, deg, cnt, flags);
  k_dis    <<<(Nn+255)/256,256,0,stream>>>(deg, dis);
  k_scan   <<<1,1024,0,stream>>>(cnt, rowptr);
  k_fill   <<<(Ee+255)/256,256,0,stream>>>(edge, rowptr, fillc, csr, flags);
  k_wx     <<<896,128,0,stream>>>(W1,b1,W2,b2,Wz,bz,Wr,br,Wc,bc, Wext, Whc, flags);
  k_px1    <<<(Tt*Nn+255)/256,256,0,stream>>>(x, dis, rowptr, csr, px1, flags);
  k_px2    <<<(Tt*Nn+255)/256,256,0,stream>>>(px1, dis, rowptr, csr, px2);

  // light path: all 12 timesteps in one dispatch (16-node wave-groups, no barriers)
  k_light<<<(NTt - NGRAPH*64)/64,256,0,stream>>>(h16, x, Wext, flags);

  // graph path: per-step propagation + GRU for the 79 graph groups
  for (int t=0; t<Tt; ++t){
    k_ph1    <<<Nn/4,256,0,stream>>>(h16, dis, rowptr, csr, phh);
    k_ph2    <<<Nn/4,256,0,stream>>>(dis, rowptr, csr, phh);
    k_mainm_g<<<NGRAPH,256,0,stream>>>(h16, x, px1, px2, phh, Wext, Whc, flags, t);
  }

  k_out<<<(NTt+255)/256,256,0,stream>>>(h16, Wo, bo, d_out, flags);
}

// Round 11
// 1162.927 us; speedup vs baseline: 2.8563x; 2.8563x over previous
//
#include <hip/hip_runtime.h>
#include <hip/hip_bf16.h>

// Problem constants (from reference)
#define Bb  32
#define Tt  12
#define Nn  5000
#define INc 2
#define Hh  128
#define HORc 12
#define Ee  80000
#define NTt (Bb*Nn)   // 160000

typedef float f4  __attribute__((ext_vector_type(4)));
typedef _Float16 h8 __attribute__((ext_vector_type(8)));
typedef _Float16 h4 __attribute__((ext_vector_type(4)));
typedef _Float16 h2 __attribute__((ext_vector_type(2)));

// hcL[64][172] (K=160 B-operand + K-ext); rL[64][132] (r*hc, stage2 output).
// HSTRIDE 172: dword-stride 86 = 22 mod 32 -> 16 distinct banks (proven).
// RSTRIDE 132: dword-stride 66 = 2 mod 32 -> 16 even banks, 2-way max (free per HW).
#define HSTRIDE 172
#define RSTRIDE 132
#define NGRAPH 79               // groups 0..78 contain nodes < Nn (graph part)

__device__ __forceinline__ float ldf(const void* p, size_t i, int isbf){
  return isbf ? __bfloat162float(((const __hip_bfloat16*)p)[i]) : ((const float*)p)[i];
}
__device__ __forceinline__ int eidx(const int* e, int i, int is64){
  return is64 ? e[2*i] : e[i];
}
// sigmoid/tanh via hardware exp+rcp.
__device__ __forceinline__ float sigm1(float x){
  return __builtin_amdgcn_rcpf(1.f + __expf(-x));
}
__device__ __forceinline__ float tanh1(float x){
  return 1.f - 2.f*__builtin_amdgcn_rcpf(1.f + __expf(2.f*x));
}

// ---------------- dtype detection ----------------
__global__ __launch_bounds__(256) void k_detect(const void* W2raw, const int* edge32, int* flags){
  __shared__ int cnt_bf, cnt_odd;
  if (threadIdx.x==0){ cnt_bf=0; cnt_odd=0; }
  __syncthreads();
  {
    unsigned w = ((const unsigned*)W2raw)[threadIdx.x];
    unsigned hb = (w>>8)&0x7Fu;
    if (hb>=0x34u && hb<=0x3Fu) atomicAdd(&cnt_bf,1);
  }
  if (threadIdx.x < 128){
    if (edge32[2*threadIdx.x+1] != 0) atomicAdd(&cnt_odd,1);
  }
  __syncthreads();
  if (threadIdx.x==0){
    flags[0] = (cnt_bf >= 128) ? 1 : 0;
    flags[1] = (cnt_odd == 0) ? 1 : 0;
  }
}

// ---------------- graph precompute ----------------
__global__ __launch_bounds__(256) void k_deg_cnt(const int* __restrict__ edge, int* deg, int* cnt,
                                                 const int* __restrict__ flags){
  int id = blockIdx.x*256 + threadIdx.x;
  int is64 = flags[1];
  if (id < Ee){
    atomicAdd(&deg[eidx(edge, id, is64)], 1);
    atomicAdd(&cnt[eidx(edge, Ee+id, is64)], 1);
  }
}

__global__ __launch_bounds__(256) void k_dis(const int* __restrict__ deg, float* dis){
  int id = blockIdx.x*256 + threadIdx.x;
  if (id < Nn){
    int d = deg[id];
    dis[id] = d > 0 ? rsqrtf((float)d) : 0.f;
  }
}

__global__ __launch_bounds__(1024) void k_scan(const int* __restrict__ cnt, int* rowptr){
  __shared__ int part[1024];
  int t = threadIdx.x;
  int base = t*5;
  int s = 0;
  #pragma unroll
  for (int j=0;j<5;j++){ int idx=base+j; if (idx<Nn) s += cnt[idx]; }
  part[t] = s; __syncthreads();
  for (int off=1; off<1024; off<<=1){
    int add = (t>=off) ? part[t-off] : 0;
    __syncthreads();
    part[t] += add;
    __syncthreads();
  }
  int run = (t>0) ? part[t-1] : 0;
  #pragma unroll
  for (int j=0;j<5;j++){
    int idx = base+j;
    if (idx < Nn){ rowptr[idx] = run; run += cnt[idx]; }
  }
  if (t == 1023) rowptr[Nn] = part[1023];
}

__global__ __launch_bounds__(256) void k_fill(const int* __restrict__ edge,
                                              const int* __restrict__ rowptr,
                                              int* fillc, int* csr,
                                              const int* __restrict__ flags){
  int id = blockIdx.x*256 + threadIdx.x;
  int is64 = flags[1];
  if (id < Ee){
    int d = eidx(edge, Ee+id, is64);
    int pos = atomicAdd(&fillc[d], 1);
    csr[rowptr[d] + pos] = eidx(edge, id, is64);
  }
}

// ---------------- weight precompute (element-parallel) ----------------
__global__ __launch_bounds__(128) void k_wx(
  const void* __restrict__ W1, const void* __restrict__ b1,
  const void* __restrict__ W2, const void* __restrict__ b2,
  const void* __restrict__ Wz, const void* __restrict__ bz,
  const void* __restrict__ Wr, const void* __restrict__ br,
  const void* __restrict__ Wc, const void* __restrict__ bc,
  _Float16* __restrict__ Wext, _Float16* __restrict__ Whc,
  const int* __restrict__ flags)
{
  int bid = blockIdx.x, f = threadIdx.x;
  int isbf = flags[0];
  if (bid < 640){
    int s = bid/160, k = bid - s*160;
    float v = 0.f;
    if (k < 128){
      if (s == 0)
        v = ldf(W2,(size_t)k*128+f,isbf) - ldf(W2,(size_t)(2*128+k)*128+f,isbf);
      else {
        const void* Wg = (s==1)?Wz:((s==2)?Wr:Wc);
        v = ldf(Wg,(size_t)(128+k)*128+f,isbf);
      }
    } else if (s == 0){
      v = (k==128) ? ldf(b2,f,isbf) : 0.f;
    } else if (k < 134){
      const void* Wg = (s==1)?Wz:((s==2)?Wr:Wc);
      int q = k - 128;
      float acc = 0.f;
      for (int j=0;j<128;j++) acc += ldf(W1,(size_t)q*128+j,isbf)*ldf(Wg,(size_t)j*128+f,isbf);
      v = acc;
    } else if (k == 134){
      const void* Wg = (s==1)?Wz:((s==2)?Wr:Wc);
      const void* bg = (s==1)?bz:((s==2)?br:bc);
      float acc = ldf(bg,f,isbf);
      for (int j=0;j<128;j++) acc += ldf(b1,j,isbf)*ldf(Wg,(size_t)j*128+f,isbf);
      v = acc;
    }
    Wext[(size_t)(s*128+f)*160 + k] = (_Float16)v;
  } else {
    int k = bid - 640;  // 0..255
    float v = (k < 128) ? ldf(W2,(size_t)(128+k)*128+f,isbf)
                        : 2.f*ldf(W2,(size_t)(2*128+(k-128))*128+f,isbf);
    Whc[(size_t)f*256 + k] = (_Float16)v;
  }
}

// ---------------- x propagation (all timesteps at once) ----------------
__global__ __launch_bounds__(256) void k_px1(
  const void* __restrict__ x, const float* __restrict__ dis,
  const int* __restrict__ rowptr, const int* __restrict__ csr, float* __restrict__ px1,
  const int* __restrict__ flags)
{
  int id = blockIdx.x*256 + threadIdx.x;
  int isbf = flags[0];
  if (id < Tt*Nn){
    int t = id / Nn, n = id - t*Nn;
    int e0 = rowptr[n], e1 = rowptr[n+1];
    float a0=0.f, a1=0.f;
    for (int e=e0;e<e1;e++){
      int s = csr[e]; float ds = dis[s];
      size_t xb = (size_t)(t*Nn+s)*2;
      a0 += ds*ldf(x,xb+0,isbf); a1 += ds*ldf(x,xb+1,isbf);
    }
    float dn = -dis[n];
    px1[id*2+0] = dn*a0; px1[id*2+1] = dn*a1;
  }
}

__global__ __launch_bounds__(256) void k_px2(
  const float* __restrict__ px1, const float* __restrict__ dis,
  const int* __restrict__ rowptr, const int* __restrict__ csr, float* __restrict__ px2)
{
  int id = blockIdx.x*256 + threadIdx.x;
  if (id < Tt*Nn){
    int t = id / Nn, n = id - t*Nn;
    int e0 = rowptr[n], e1 = rowptr[n+1];
    float a0=0.f, a1=0.f;
    for (int e=e0;e<e1;e++){
      int s = csr[e]; float ds = dis[s];
      const float* pp = px1 + (size_t)(t*Nn+s)*2;
      a0 += ds*pp[0]; a1 += ds*pp[1];
    }
    float dn = -dis[n];
    px2[id*2+0] = dn*a0; px2[id*2+1] = dn*a1;
  }
}

// ---------------- per-step h propagation (fp16, 4 nodes/block) ----------------
__global__ __launch_bounds__(256) void k_ph1(
  const _Float16* __restrict__ h16, const float* __restrict__ dis,
  const int* __restrict__ rowptr, const int* __restrict__ csr,
  _Float16* __restrict__ phh)
{
  int n = blockIdx.x*4 + (threadIdx.x>>6);
  int f2 = threadIdx.x & 63;
  int e0 = rowptr[n], e1 = rowptr[n+1];
  float a0=0.f, a1=0.f, b0=0.f, b1=0.f;
  int e = e0;
  for (; e+3 < e1; e += 4){
    int s0=csr[e], s1=csr[e+1], s2=csr[e+2], s3=csr[e+3];
    float d0=dis[s0], d1=dis[s1], d2=dis[s2], d3=dis[s3];
    h2 v0 = *(const h2*)(h16 + (size_t)s0*128 + 2*f2);
    h2 v1 = *(const h2*)(h16 + (size_t)s1*128 + 2*f2);
    h2 v2 = *(const h2*)(h16 + (size_t)s2*128 + 2*f2);
    h2 v3 = *(const h2*)(h16 + (size_t)s3*128 + 2*f2);
    a0 += d0*(float)v0[0]; a1 += d0*(float)v0[1];
    b0 += d1*(float)v1[0]; b1 += d1*(float)v1[1];
    a0 += d2*(float)v2[0]; a1 += d2*(float)v2[1];
    b0 += d3*(float)v3[0]; b1 += d3*(float)v3[1];
  }
  for (; e < e1; e++){
    int s = csr[e]; float ds = dis[s];
    h2 v = *(const h2*)(h16 + (size_t)s*128 + 2*f2);
    a0 += ds*(float)v[0]; a1 += ds*(float)v[1];
  }
  a0 += b0; a1 += b1;
  float dn = -dis[n];
  h2 o; o[0]=(_Float16)(dn*a0); o[1]=(_Float16)(dn*a1);
  *(h2*)(phh + (size_t)n*256 + 2*f2) = o;
}

__global__ __launch_bounds__(256) void k_ph2(
  const float* __restrict__ dis,
  const int* __restrict__ rowptr, const int* __restrict__ csr,
  _Float16* __restrict__ phh)
{
  int n = blockIdx.x*4 + (threadIdx.x>>6);
  int f2 = threadIdx.x & 63;
  int e0 = rowptr[n], e1 = rowptr[n+1];
  float a0=0.f, a1=0.f, b0=0.f, b1=0.f;
  int e = e0;
  for (; e+3 < e1; e += 4){
    int s0=csr[e], s1=csr[e+1], s2=csr[e+2], s3=csr[e+3];
    float d0=dis[s0], d1=dis[s1], d2=dis[s2], d3=dis[s3];
    h2 v0 = *(const h2*)(phh + (size_t)s0*256 + 2*f2);
    h2 v1 = *(const h2*)(phh + (size_t)s1*256 + 2*f2);
    h2 v2 = *(const h2*)(phh + (size_t)s2*256 + 2*f2);
    h2 v3 = *(const h2*)(phh + (size_t)s3*256 + 2*f2);
    a0 += d0*(float)v0[0]; a1 += d0*(float)v0[1];
    b0 += d1*(float)v1[0]; b1 += d1*(float)v1[1];
    a0 += d2*(float)v2[0]; a1 += d2*(float)v2[1];
    b0 += d3*(float)v3[0]; b1 += d3*(float)v3[1];
  }
  for (; e < e1; e++){
    int s = csr[e]; float ds = dis[s];
    h2 v = *(const h2*)(phh + (size_t)s*256 + 2*f2);
    a0 += ds*(float)v[0]; a1 += ds*(float)v[1];
  }
  a0 += b0; a1 += b1;
  float dn = -dis[n];
  h2 o; o[0]=(_Float16)(dn*a0); o[1]=(_Float16)(dn*a1);
  *(h2*)(phh + (size_t)n*256 + 128 + 2*f2) = o;
}

// ---------------- fused GRU step, MFMA (round-4 body + weight hoist + rL) ----------------
// Round-4 structure (unified 2500-WG per-step dispatch, 64-node groups, wave = one
// 32-feature panel x 4 tiles, 2 barriers; best total 1136us, 108 VGPR clean).
// Diagnosis (rounds 0-10): ~30-33 group-steps/us invariant in every clean config,
// independent of barriers/launch/occupancy caps -> the serial chain is the per-ks
// "load a0,a1 -> 8 MFMA" pattern: 5 L2 round-trips per stage (~400-600cy each).
// Fix: (1) hoist all 10 weight loads per stage into wv0[5]/wv1[5] -> 1 round-trip;
// (2) pay the +20 VGPR by dropping the ba/bc reg caches (80 VGPR): stage 2 writes
// r*hc to a separate rL buffer, so stages 1-3 re-read B per-ks from LDS race-free.
// Stage 0 stays byte-identical to round 4 (proven codegen). LDS 22016 -> 38912 B.

__global__ __launch_bounds__(256, 2) void k_mainm(
    _Float16* __restrict__ h16, const void* __restrict__ x,
    const float* __restrict__ px1, const float* __restrict__ px2,
    const _Float16* __restrict__ phh,
    const _Float16* __restrict__ Wext, const _Float16* __restrict__ Whc,
    const int* __restrict__ flags, int t)
{
  __shared__ _Float16 hcL[64*HSTRIDE];   // 22016 B
  __shared__ _Float16 rL[64*RSTRIDE];    // 16896 B
  int tid = threadIdx.x;
  int w = tid >> 6, lane = tid & 63;
  int fp = w;                        // feature panel 0..3 (32 feats each)
  int gbase = blockIdx.x*64;         // 64-node group
  int n16 = lane & 15, g = lane >> 4, q8 = g*8;

  // K-extension slots: hcL[n][128..134] = {x0,x1,u1a,u1b,u2a,u2b,1}, 135..159 = 0
  if (tid < 64){
    int n = tid;
    _Float16* row = hcL + n*HSTRIDE;
    for (int k=135;k<160;k++) row[k] = (_Float16)0.f;
    int isbf = flags[0];
    int i = gbase + n;
    int b = i / Nn, nn2 = i - b*Nn;
    size_t xb = ((size_t)(b*Tt + t)*Nn + nn2)*2;
    float x0 = ldf(x,xb+0,isbf), x1 = ldf(x,xb+1,isbf);
    float u1a=0.f,u1b=0.f,u2a=-x0,u2b=-x1;   // nodes >= Nn: Tx1=0, Tx2=-x
    if (i < Nn){
      u1a = px1[(t*Nn+i)*2+0]; u1b = px1[(t*Nn+i)*2+1];
      u2a = 2.f*px2[(t*Nn+i)*2+0] - x0; u2b = 2.f*px2[(t*Nn+i)*2+1] - x1;
    }
    row[128]=(_Float16)x0;  row[129]=(_Float16)x1;
    row[130]=(_Float16)u1a; row[131]=(_Float16)u1b;
    row[132]=(_Float16)u2a; row[133]=(_Float16)u2b;
    row[134]=(_Float16)1.f;
  }

  h8 zz = {0,0,0,0,0,0,0,0};
  h8 biasv = zz;
  if (g==0) biasv[0] = (_Float16)1.f;   // bias slot k=128 (st0 B col)
  f4 z4 = {0.f,0.f,0.f,0.f};

  // ---- stage 0: hc = h@(W2[0]-W2[2]) + b2 (+ graph K-ext) -- round-4 verbatim ----
  f4 acc[4][2];
  #pragma unroll
  for (int tl=0;tl<4;tl++){ acc[tl][0]=z4; acc[tl][1]=z4; }
  {
    h8 bf[4][4];
    #pragma unroll
    for (int tl=0;tl<4;tl++){
      const _Float16* hp = h16 + (size_t)(gbase + tl*16 + n16)*128 + q8;
      #pragma unroll
      for (int ks=0;ks<4;ks++) bf[tl][ks] = *(const h8*)(hp + ks*32);
    }
    const _Float16* Wa = Wext + (size_t)(fp*32 + n16)*160 + q8;
    #pragma unroll
    for (int ks=0; ks<5; ks++){
      h8 a0 = *(const h8*)(Wa + ks*32);
      h8 a1 = *(const h8*)(Wa + 16*160 + ks*32);
      #pragma unroll
      for (int tl=0;tl<4;tl++){
        h8 b = (ks<4) ? bf[tl][ks] : biasv;
        acc[tl][0] = __builtin_amdgcn_mfma_f32_16x16x32_f16(a0, b, acc[tl][0], 0,0,0);
        acc[tl][1] = __builtin_amdgcn_mfma_f32_16x16x32_f16(a1, b, acc[tl][1], 0,0,0);
      }
    }
  }
  if (gbase < Nn){                      // block-uniform graph part (79 of 2500 blocks)
    const _Float16* Wb = Whc + (size_t)(fp*32 + n16)*256 + q8;
    #pragma unroll
    for (int pass=0; pass<2; pass++){
      h8 bg[2][8];
      #pragma unroll
      for (int tt=0;tt<2;tt++){
        int node = gbase + (pass*2+tt)*16 + n16;
        bool ok = node < Nn;
        const _Float16* pp = phh + (size_t)(ok ? node : 0)*256 + q8;
        #pragma unroll
        for (int ks=0;ks<8;ks++){
          h8 v = *(const h8*)(pp + ks*32);
          bg[tt][ks] = ok ? v : zz;
        }
      }
      #pragma unroll
      for (int ks=0; ks<8; ks++){
        h8 a0 = *(const h8*)(Wb + ks*32);
        h8 a1 = *(const h8*)(Wb + 16*256 + ks*32);
        #pragma unroll
        for (int tt=0;tt<2;tt++){
          acc[pass*2+tt][0] = __builtin_amdgcn_mfma_f32_16x16x32_f16(a0, bg[tt][ks], acc[pass*2+tt][0], 0,0,0);
          acc[pass*2+tt][1] = __builtin_amdgcn_mfma_f32_16x16x32_f16(a1, bg[tt][ks], acc[pass*2+tt][1], 0,0,0);
        }
      }
    }
  }
  #pragma unroll
  for (int tl=0;tl<4;tl++)
    #pragma unroll
    for (int hh=0;hh<2;hh++){
      int fb = fp*32 + hh*16 + g*4;
      f4 a = acc[tl][hh];
      h4 o;
      #pragma unroll
      for (int r=0;r<4;r++) o[r] = (_Float16)a[r];
      *(h4*)&hcL[(tl*16+n16)*HSTRIDE + fb] = o;
    }

  __syncthreads();   // barrier 1: hc (all 128 feats) + K-ext complete

  // ---- stage 1: z (hoisted weights; B per-ks from hcL; z stays in regs) ----
  h4 zr[4][2];
  {
    h8 wv0[5], wv1[5];
    const _Float16* Wa = Wext + 1*20480 + (size_t)(fp*32 + n16)*160 + q8;
    #pragma unroll
    for (int ks=0; ks<5; ks++){
      wv0[ks] = *(const h8*)(Wa + ks*32);
      wv1[ks] = *(const h8*)(Wa + 16*160 + ks*32);
    }
    f4 a[4][2];
    #pragma unroll
    for (int tl=0;tl<4;tl++){ a[tl][0]=z4; a[tl][1]=z4; }
    #pragma unroll
    for (int ks=0; ks<5; ks++){
      h8 b0 = *(const h8*)&hcL[(0*16+n16)*HSTRIDE + ks*32 + q8];
      h8 b1 = *(const h8*)&hcL[(1*16+n16)*HSTRIDE + ks*32 + q8];
      h8 b2 = *(const h8*)&hcL[(2*16+n16)*HSTRIDE + ks*32 + q8];
      h8 b3 = *(const h8*)&hcL[(3*16+n16)*HSTRIDE + ks*32 + q8];
      a[0][0] = __builtin_amdgcn_mfma_f32_16x16x32_f16(wv0[ks], b0, a[0][0], 0,0,0);
      a[0][1] = __builtin_amdgcn_mfma_f32_16x16x32_f16(wv1[ks], b0, a[0][1], 0,0,0);
      a[1][0] = __builtin_amdgcn_mfma_f32_16x16x32_f16(wv0[ks], b1, a[1][0], 0,0,0);
      a[1][1] = __builtin_amdgcn_mfma_f32_16x16x32_f16(wv1[ks], b1, a[1][1], 0,0,0);
      a[2][0] = __builtin_amdgcn_mfma_f32_16x16x32_f16(wv0[ks], b2, a[2][0], 0,0,0);
      a[2][1] = __builtin_amdgcn_mfma_f32_16x16x32_f16(wv1[ks], b2, a[2][1], 0,0,0);
      a[3][0] = __builtin_amdgcn_mfma_f32_16x16x32_f16(wv0[ks], b3, a[3][0], 0,0,0);
      a[3][1] = __builtin_amdgcn_mfma_f32_16x16x32_f16(wv1[ks], b3, a[3][1], 0,0,0);
    }
    #pragma unroll
    for (int tl=0;tl<4;tl++)
      #pragma unroll
      for (int hh=0;hh<2;hh++){
        f4 av = a[tl][hh];
        h4 o;
        #pragma unroll
        for (int r=0;r<4;r++) o[r] = (_Float16)sigm1(av[r]);
        zr[tl][hh] = o;
      }
  }

  // ---- stage 2: r; write r*hc to rL (hcL untouched -> race-free re-reads) ----
  {
    h8 wv0[5], wv1[5];
    const _Float16* Wa = Wext + 2*20480 + (size_t)(fp*32 + n16)*160 + q8;
    #pragma unroll
    for (int ks=0; ks<5; ks++){
      wv0[ks] = *(const h8*)(Wa + ks*32);
      wv1[ks] = *(const h8*)(Wa + 16*160 + ks*32);
    }
    f4 a[4][2];
    #pragma unroll
    for (int tl=0;tl<4;tl++){ a[tl][0]=z4; a[tl][1]=z4; }
    #pragma unroll
    for (int ks=0; ks<5; ks++){
      h8 b0 = *(const h8*)&hcL[(0*16+n16)*HSTRIDE + ks*32 + q8];
      h8 b1 = *(const h8*)&hcL[(1*16+n16)*HSTRIDE + ks*32 + q8];
      h8 b2 = *(const h8*)&hcL[(2*16+n16)*HSTRIDE + ks*32 + q8];
      h8 b3 = *(const h8*)&hcL[(3*16+n16)*HSTRIDE + ks*32 + q8];
      a[0][0] = __builtin_amdgcn_mfma_f32_16x16x32_f16(wv0[ks], b0, a[0][0], 0,0,0);
      a[0][1] = __builtin_amdgcn_mfma_f32_16x16x32_f16(wv1[ks], b0, a[0][1], 0,0,0);
      a[1][0] = __builtin_amdgcn_mfma_f32_16x16x32_f16(wv0[ks], b1, a[1][0], 0,0,0);
      a[1][1] = __builtin_amdgcn_mfma_f32_16x16x32_f16(wv1[ks], b1, a[1][1], 0,0,0);
      a[2][0] = __builtin_amdgcn_mfma_f32_16x16x32_f16(wv0[ks], b2, a[2][0], 0,0,0);
      a[2][1] = __builtin_amdgcn_mfma_f32_16x16x32_f16(wv1[ks], b2, a[2][1], 0,0,0);
      a[3][0] = __builtin_amdgcn_mfma_f32_16x16x32_f16(wv0[ks], b3, a[3][0], 0,0,0);
      a[3][1] = __builtin_amdgcn_mfma_f32_16x16x32_f16(wv1[ks], b3, a[3][1], 0,0,0);
    }
    #pragma unroll
    for (int tl=0;tl<4;tl++)
      #pragma unroll
      for (int hh=0;hh<2;hh++){
        int fb = fp*32 + hh*16 + g*4;
        int nn = tl*16 + n16;
        h4 hcv = *(const h4*)&hcL[nn*HSTRIDE + fb];
        f4 av = a[tl][hh];
        h4 o;
        #pragma unroll
        for (int r=0;r<4;r++) o[r] = (_Float16)(sigm1(av[r]) * (float)hcv[r]);
        *(h4*)&rL[nn*RSTRIDE + fb] = o;
      }
  }

  __syncthreads();   // barrier 2: rL complete

  // ---- stage 3: c + blend, write h16 (B: ks<4 from rL, ks=4 K-ext from hcL) ----
  {
    h8 wv0[5], wv1[5];
    const _Float16* Wa = Wext + 3*20480 + (size_t)(fp*32 + n16)*160 + q8;
    #pragma unroll
    for (int ks=0; ks<5; ks++){
      wv0[ks] = *(const h8*)(Wa + ks*32);
      wv1[ks] = *(const h8*)(Wa + 16*160 + ks*32);
    }
    f4 a[4][2];
    #pragma unroll
    for (int tl=0;tl<4;tl++){ a[tl][0]=z4; a[tl][1]=z4; }
    #pragma unroll
    for (int ks=0; ks<5; ks++){
      h8 b0, b1, b2, b3;
      if (ks < 4){
        b0 = *(const h8*)&rL[(0*16+n16)*RSTRIDE + ks*32 + q8];
        b1 = *(const h8*)&rL[(1*16+n16)*RSTRIDE + ks*32 + q8];
        b2 = *(const h8*)&rL[(2*16+n16)*RSTRIDE + ks*32 + q8];
        b3 = *(const h8*)&rL[(3*16+n16)*RSTRIDE + ks*32 + q8];
      } else {
        b0 = *(const h8*)&hcL[(0*16+n16)*HSTRIDE + 128 + q8];
        b1 = *(const h8*)&hcL[(1*16+n16)*HSTRIDE + 128 + q8];
        b2 = *(const h8*)&hcL[(2*16+n16)*HSTRIDE + 128 + q8];
        b3 = *(const h8*)&hcL[(3*16+n16)*HSTRIDE + 128 + q8];
      }
      a[0][0] = __builtin_amdgcn_mfma_f32_16x16x32_f16(wv0[ks], b0, a[0][0], 0,0,0);
      a[0][1] = __builtin_amdgcn_mfma_f32_16x16x32_f16(wv1[ks], b0, a[0][1], 0,0,0);
      a[1][0] = __builtin_amdgcn_mfma_f32_16x16x32_f16(wv0[ks], b1, a[1][0], 0,0,0);
      a[1][1] = __builtin_amdgcn_mfma_f32_16x16x32_f16(wv1[ks], b1, a[1][1], 0,0,0);
      a[2][0] = __builtin_amdgcn_mfma_f32_16x16x32_f16(wv0[ks], b2, a[2][0], 0,0,0);
      a[2][1] = __builtin_amdgcn_mfma_f32_16x16x32_f16(wv1[ks], b2, a[2][1], 0,0,0);
      a[3][0] = __builtin_amdgcn_mfma_f32_16x16x32_f16(wv0[ks], b3, a[3][0], 0,0,0);
      a[3][1] = __builtin_amdgcn_mfma_f32_16x16x32_f16(wv1[ks], b3, a[3][1], 0,0,0);
    }
    #pragma unroll
    for (int tl=0;tl<4;tl++)
      #pragma unroll
      for (int hh=0;hh<2;hh++){
        int fb = fp*32 + hh*16 + g*4;
        int nn = tl*16 + n16;
        int gi = gbase + nn;
        h4 ho = *(const h4*)(h16 + (size_t)gi*128 + fb);
        h4 zv = zr[tl][hh];
        f4 av = a[tl][hh];
        h4 o;
        #pragma unroll
        for (int r=0;r<4;r++){
          float z = (float)zv[r];
          o[r] = (_Float16)(z*(float)ho[r] + (1.f - z)*tanh1(av[r]));
        }
        *(h4*)(h16 + (size_t)gi*128 + fb) = o;
      }
  }
}

// ---------------- output projection ----------------
__global__ __launch_bounds__(256) void k_out(
  const _Float16* __restrict__ h16, const void* __restrict__ Wo,
  const void* __restrict__ bo, void* __restrict__ out,
  const int* __restrict__ flags)
{
  __shared__ float wol[128*HORc];
  __shared__ float wob[HORc];
  int isbf = flags[0];
  for (int idx=threadIdx.x; idx<128*HORc; idx+=256) wol[idx] = ldf(Wo, idx, isbf);
  if (threadIdx.x < HORc) wob[threadIdx.x] = ldf(bo, threadIdx.x, isbf);
  __syncthreads();

  int i = blockIdx.x*256 + threadIdx.x;
  if (i < NTt){
    float acc[HORc];
    #pragma unroll
    for (int j=0;j<HORc;j++) acc[j] = wob[j];
    const _Float16* hp = h16 + (size_t)i*128;
    for (int kb=0;kb<16;kb++){
      h8 hv = *(const h8*)(hp + kb*8);
      #pragma unroll
      for (int j=0;j<8;j++){
        float hvf = (float)hv[j];
        #pragma unroll
        for (int jj=0;jj<HORc;jj++) acc[jj] += hvf * wol[(kb*8+j)*HORc + jj];
      }
    }
    int b = i / Nn, n = i - b*Nn;
    #pragma unroll
    for (int j=0;j<HORc;j++){
      size_t oi = (size_t)(b*HORc+j)*Nn + n;
      if (isbf) ((__hip_bfloat16*)out)[oi] = __float2bfloat16(acc[j]);
      else      ((float*)out)[oi] = acc[j];
    }
  }
}

// ---------------- host ----------------
extern "C" void kernel_launch(void* const* d_in, const int* in_sizes, int n_in,
                              void* d_out, int out_size, void* d_ws, size_t ws_size,
                              hipStream_t stream) {
  (void)in_sizes; (void)n_in; (void)out_size; (void)ws_size;
  const void* x   = d_in[0];
  const int*  edge= (const int*)d_in[1];
  const void* W1  = d_in[2];
  const void* b1  = d_in[3];
  const void* W2  = d_in[4];
  const void* b2  = d_in[5];
  const void* Wz  = d_in[6];
  const void* bz  = d_in[7];
  const void* Wr  = d_in[8];
  const void* br  = d_in[9];
  const void* Wc  = d_in[10];
  const void* bc  = d_in[11];
  const void* Wo  = d_in[12];
  const void* bo  = d_in[13];

  char* ws = (char*)d_ws;
  size_t off = 0;
  auto alloc = [&](size_t bytes)->char*{
    char* p = ws + off;
    off += (bytes + 255) & ~(size_t)255;
    return p;
  };
  _Float16* h16  = (_Float16*)alloc((size_t)NTt*128*2);   // 41 MB, zeroed
  int*   deg   = (int*)  alloc(Nn*4);                     // zeroed
  int*   cnt   = (int*)  alloc(Nn*4);                     // zeroed
  int*   fillc = (int*)  alloc(Nn*4);                     // zeroed
  size_t zlen = off;
  int*   flags = (int*)  alloc(16*4);
  float* dis   = (float*)alloc(Nn*4);
  int*   rowptr= (int*)  alloc((Nn+1)*4);
  int*   csr   = (int*)  alloc(Ee*4);
  float* px1   = (float*)alloc((size_t)Tt*Nn*2*4);
  float* px2   = (float*)alloc((size_t)Tt*Nn*2*4);
  _Float16* phh  = (_Float16*)alloc((size_t)5120*256*2);  // ph1|ph2 fp16 rows (padded)
  _Float16* Wext = (_Float16*)alloc((size_t)4*128*160*2);
  _Float16* Whc  = (_Float16*)alloc((size_t)128*256*2);

  hipMemsetAsync(d_ws, 0, zlen, stream);

  k_detect <<<1,256,0,stream>>>(W2, edge, flags);
  k_deg_cnt<<<(Ee+255)/256,256,0,stream>>>(edge, deg, cnt, flags);
  k_dis    <<<(Nn+255)/256,256,0,stream>>>(deg, dis);
  k_scan   <<<1,1024,0,stream>>>(cnt, rowptr);
  k_fill   <<<(Ee+255)/256,256,0,stream>>>(edge, rowptr, fillc, csr, flags);
  k_wx     <<<896,128,0,stream>>>(W1,b1,W2,b2,Wz,bz,Wr,br,Wc,bc, Wext, Whc, flags);
  k_px1    <<<(Tt*Nn+255)/256,256,0,stream>>>(x, dis, rowptr, csr, px1, flags);
  k_px2    <<<(Tt*Nn+255)/256,256,0,stream>>>(px1, dis, rowptr, csr, px2);

  for (int t=0; t<Tt; ++t){
    k_ph1  <<<Nn/4,256,0,stream>>>(h16, dis, rowptr, csr, phh);
    k_ph2  <<<Nn/4,256,0,stream>>>(dis, rowptr, csr, phh);
    k_mainm<<<NTt/64,256,0,stream>>>(h16, x, px1, px2, phh, Wext, Whc, flags, t);
  }

  k_out<<<(NTt+255)/256,256,0,stream>>>(h16, Wo, bo, d_out, flags);
}